// Round 3
// baseline (934.719 us; speedup 1.0000x reference)
//
#include <hip/hip_runtime.h>
#include <hip/hip_bf16.h>
#include <math.h>

#define NB 32
#define NQ 2048
#define NK 512
#define NE 16
#define NH 32
#define NL 20
#define NHID 50
#define NO 41

// ws layout (floats):
// val  : [32][512][64] @ 0        (1,048,576)
// ktab : [512][16]     @ 1048576  (8,192)
// total 1,056,768 floats = 4.2 MB

__global__ __launch_bounds__(256) void prep_kernel(
    const float* __restrict__ refq, const float* __restrict__ Wk,
    const float* __restrict__ bk, float* __restrict__ ktab) {
  const int r = blockIdx.x * 256 + threadIdx.x;
  if (r >= NK) return;
  const float divs[8] = {1.0f, 0.74989421f, 0.56234133f, 0.42169650f,
                         0.31622777f, 0.23713737f, 0.17782794f, 0.13335214f};
  float pos = refq[r];
  float emb[NE];
#pragma unroll
  for (int m = 0; m < 8; ++m) {
    float a = 48.0f * pos * divs[m];
    emb[2 * m] = sinf(a);
    emb[2 * m + 1] = cosf(a);
  }
#pragma unroll
  for (int e = 0; e < NE; ++e) {
    float acc = bk[e];
#pragma unroll
    for (int i = 0; i < NE; ++i) acc += emb[i] * Wk[e * NE + i];
    ktab[r * NE + e] = acc;
  }
}

// One block per batch b; grp 0 = forward chain, grp 1 = backward chain (both
// share z[b], staged once in LDS). Lane (grp, j) owns hidden unit j. Input
// gates computed on the fly from LDS z (no gi workspace).
__global__ __launch_bounds__(64) void gru_kernel(
    const float* __restrict__ z,
    const float* __restrict__ Wih_f, const float* __restrict__ bih_f,
    const float* __restrict__ Whh_f, const float* __restrict__ bhh_f,
    const float* __restrict__ Wih_b, const float* __restrict__ bih_b,
    const float* __restrict__ Whh_b, const float* __restrict__ bhh_b,
    float* __restrict__ val) {
  __shared__ __align__(16) float zs[NK * NL];  // 40 KB
  __shared__ __align__(16) float hbuf[64];     // [grp][32]
  const int l = threadIdx.x;
  const int grp = l >> 5, j = l & 31;
  const int b = blockIdx.x;
  const int dir = grp;
  const float* __restrict__ zb = z + (size_t)b * NK * NL;
  for (int i = l; i < NK * NL; i += 64) zs[i] = zb[i];

  const float* __restrict__ Wih = dir ? Wih_b : Wih_f;
  const float* __restrict__ bih = dir ? bih_b : bih_f;
  const float* __restrict__ Whh = dir ? Whh_b : Whh_f;
  const float* __restrict__ bhh = dir ? bhh_b : bhh_f;

  float ur[NL], uz[NL], un[NL];
#pragma unroll
  for (int i = 0; i < NL; ++i) {
    ur[i] = Wih[j * NL + i];
    uz[i] = Wih[(j + 32) * NL + i];
    un[i] = Wih[(j + 64) * NL + i];
  }
  float wr[32], wz[32], wn[32];
#pragma unroll
  for (int i = 0; i < 32; ++i) {
    wr[i] = Whh[j * 32 + i];
    wz[i] = Whh[(j + 32) * 32 + i];
    wn[i] = Whh[(j + 64) * 32 + i];
  }
  const float bir = bih[j], biz = bih[j + 32], bin_ = bih[j + 64];
  const float bhr = bhh[j], bhz = bhh[j + 32], bhn = bhh[j + 64];
  hbuf[l] = 0.0f;
  __syncthreads();

  for (int s = 0; s < NK; ++s) {
    const int tt = dir ? (NK - 1 - s) : s;
    // input-side gates from LDS z (wave-uniform broadcast reads)
    float gir = bir, giz = biz, gin = bin_;
    const float* zrow = &zs[tt * NL];
#pragma unroll
    for (int i = 0; i < NL; ++i) {
      const float zi = zrow[i];
      gir += ur[i] * zi;
      giz += uz[i] * zi;
      gin += un[i] * zi;
    }
    // recurrent gates
    float pr = 0.f, pz = 0.f, pn = 0.f;
#pragma unroll
    for (int t = 0; t < 8; ++t) {
      const float4 hv = *(const float4*)&hbuf[grp * 32 + t * 4];
      pr += wr[t * 4 + 0] * hv.x + wr[t * 4 + 1] * hv.y +
            wr[t * 4 + 2] * hv.z + wr[t * 4 + 3] * hv.w;
      pz += wz[t * 4 + 0] * hv.x + wz[t * 4 + 1] * hv.y +
            wz[t * 4 + 2] * hv.z + wz[t * 4 + 3] * hv.w;
      pn += wn[t * 4 + 0] * hv.x + wn[t * 4 + 1] * hv.y +
            wn[t * 4 + 2] * hv.z + wn[t * 4 + 3] * hv.w;
    }
    const float hj = hbuf[grp * 32 + j];
    const float rg = 1.0f / (1.0f + __expf(-(gir + pr + bhr)));
    const float ug = 1.0f / (1.0f + __expf(-(giz + pz + bhz)));
    const float ng = tanhf(gin + rg * (pn + bhn));
    const float hnew = (1.0f - ug) * ng + ug * hj;
    __syncthreads();  // old-h reads complete
    hbuf[grp * 32 + j] = hnew;
    val[((size_t)b * NK + tt) * 64 + dir * 32 + j] = hnew;
    __syncthreads();  // new h visible
  }
}

__global__ __launch_bounds__(256) void attn_kernel(
    const float* __restrict__ tsteps, const float* __restrict__ ktab,
    const float* __restrict__ val,
    const float* __restrict__ Wq, const float* __restrict__ bq,
    const float* __restrict__ Wv, const float* __restrict__ bv,
    const float* __restrict__ W1, const float* __restrict__ b1,
    const float* __restrict__ W2, const float* __restrict__ b2,
    float* __restrict__ out) {
  __shared__ __align__(16) float kt[NK * NE];    // 32 KB
  __shared__ __align__(16) float w1s[NHID * 64]; // 12.8 KB
  __shared__ float wqs[NE * NE];
  __shared__ float bqs[NE], b1s[NHID];
  const int tid = threadIdx.x;
  for (int i = tid; i < NK * NE; i += 256) kt[i] = ktab[i];
  for (int i = tid; i < NHID * 64; i += 256) w1s[i] = W1[i];
  for (int i = tid; i < NE * NE; i += 256) wqs[i] = Wq[i];
  if (tid < NE) bqs[tid] = bq[tid];
  if (tid < NHID) b1s[tid] = b1[tid];
  __syncthreads();

  const int row = blockIdx.x * 256 + tid;  // b*2048 + qi
  const int b = row >> 11;
  const float pos = tsteps[row];
  const float divs[8] = {1.0f, 0.74989421f, 0.56234133f, 0.42169650f,
                         0.31622777f, 0.23713737f, 0.17782794f, 0.13335214f};
  float emb[NE];
#pragma unroll
  for (int m = 0; m < 8; ++m) {
    float a = 48.0f * pos * divs[m];
    emb[2 * m] = sinf(a);
    emb[2 * m + 1] = cosf(a);
  }
  float q[NE];
#pragma unroll
  for (int e = 0; e < NE; ++e) {
    float acc = bqs[e];
#pragma unroll
    for (int i = 0; i < NE; ++i) acc += emb[i] * wqs[e * NE + i];
    q[e] = acc;
  }
  const float* __restrict__ vb = val + (size_t)b * NK * 64;
  float att[64];
#pragma unroll
  for (int d = 0; d < 64; ++d) att[d] = 0.f;
  float lsum = 0.f;
  // scores O(1) (0.1-scale weights): exp without max-sub safe in fp32
#pragma unroll 2
  for (int k = 0; k < NK; ++k) {
    const float4* kr = (const float4*)&kt[k * NE];
    float s = 0.f;
#pragma unroll
    for (int e4 = 0; e4 < 4; ++e4) {
      float4 kk = kr[e4];
      s += q[e4 * 4 + 0] * kk.x + q[e4 * 4 + 1] * kk.y +
           q[e4 * 4 + 2] * kk.z + q[e4 * 4 + 3] * kk.w;
    }
    float p = __expf(s * 0.25f);
    lsum += p;
    const float4* vr = (const float4*)(vb + k * 64);  // wave-uniform broadcast
#pragma unroll
    for (int d4 = 0; d4 < 16; ++d4) {
      float4 vv = vr[d4];
      att[d4 * 4 + 0] += p * vv.x;
      att[d4 * 4 + 1] += p * vv.y;
      att[d4 * 4 + 2] += p * vv.z;
      att[d4 * 4 + 3] += p * vv.w;
    }
  }
  const float inv = 1.0f / lsum;
#pragma unroll
  for (int d = 0; d < 64; ++d) att[d] *= inv;

  // fold v-projection: softmax rows sum to 1 => P@(val*Wv^T+bv) == (P@val)*Wv^T+bv
  float av[64];
#pragma unroll
  for (int d = 0; d < 64; ++d) {
    float acc = bv[d];
#pragma unroll
    for (int i = 0; i < 64; ++i) acc += att[i] * Wv[d * 64 + i];
    av[d] = acc;
  }

  float h[NHID];
#pragma unroll
  for (int o = 0; o < NHID; ++o) {
    float acc = b1s[o];
    const float4* wr4 = (const float4*)&w1s[o * 64];
#pragma unroll
    for (int i4 = 0; i4 < 16; ++i4) {
      float4 ww = wr4[i4];
      acc += av[i4 * 4 + 0] * ww.x + av[i4 * 4 + 1] * ww.y +
             av[i4 * 4 + 2] * ww.z + av[i4 * 4 + 3] * ww.w;
    }
    h[o] = fmaxf(acc, 0.f);
  }
  float* orow = out + (size_t)row * NO;
#pragma unroll
  for (int oo = 0; oo < NO; ++oo) {
    float acc = b2[oo];
#pragma unroll
    for (int o = 0; o < NHID; ++o) acc += h[o] * W2[oo * NHID + o];
    orow[oo] = acc;  // fp32 output: reference output dtype is float32
  }
}

extern "C" void kernel_launch(void* const* d_in, const int* in_sizes, int n_in,
                              void* d_out, int out_size, void* d_ws, size_t ws_size,
                              hipStream_t stream) {
  const float* z = (const float*)d_in[0];
  const float* ts = (const float*)d_in[1];
  const float* refq = (const float*)d_in[2];
  const float* Wih_f = (const float*)d_in[3];
  const float* Whh_f = (const float*)d_in[4];
  const float* bih_f = (const float*)d_in[5];
  const float* bhh_f = (const float*)d_in[6];
  const float* Wih_b = (const float*)d_in[7];
  const float* Whh_b = (const float*)d_in[8];
  const float* bih_b = (const float*)d_in[9];
  const float* bhh_b = (const float*)d_in[10];
  const float* Wq = (const float*)d_in[11];
  const float* bq = (const float*)d_in[12];
  const float* Wk = (const float*)d_in[13];
  const float* bk = (const float*)d_in[14];
  const float* Wv = (const float*)d_in[15];
  const float* bv = (const float*)d_in[16];
  const float* W1 = (const float*)d_in[17];
  const float* b1 = (const float*)d_in[18];
  const float* W2 = (const float*)d_in[19];
  const float* b2 = (const float*)d_in[20];

  float* ws = (float*)d_ws;
  float* val = ws;                // 1,048,576 floats
  float* ktab = ws + 1048576;     // 8,192 floats
  float* out = (float*)d_out;

  prep_kernel<<<2, 256, 0, stream>>>(refq, Wk, bk, ktab);
  gru_kernel<<<32, 64, 0, stream>>>(z, Wih_f, bih_f, Whh_f, bhh_f,
                                    Wih_b, bih_b, Whh_b, bhh_b, val);
  attn_kernel<<<256, 256, 0, stream>>>(ts, ktab, val, Wq, bq, Wv, bv,
                                       W1, b1, W2, b2, out);
}